// Round 5
// baseline (3865.972 us; speedup 1.0000x reference)
//
#include <hip/hip_runtime.h>
#include <hip/hip_bf16.h>
#include <math.h>

#define NSRC 8192
#define NTGT 8192
#define DIM 64

// ---------------------------------------------------------------------------
// helpers
// ---------------------------------------------------------------------------
__device__ __forceinline__ float wave_reduce_sum(float x) {
#pragma unroll
  for (int off = 32; off > 0; off >>= 1) x += __shfl_down(x, off, 64);
  return x;
}

__device__ __forceinline__ float bflo(unsigned int u) {  // low bf16 of a u32
  return __uint_as_float(u << 16);
}
__device__ __forceinline__ float bfhi(unsigned int u) {  // high bf16 of a u32
  return __uint_as_float(u & 0xFFFF0000u);
}

// ---------------------------------------------------------------------------
// kernel 1: squared norms of source rows and target rows
// ---------------------------------------------------------------------------
__global__ __launch_bounds__(256) void norms_k(const float* __restrict__ S,
                                               const float* __restrict__ T,
                                               float* __restrict__ s2,
                                               float* __restrict__ t2) {
  int i = blockIdx.x * 256 + threadIdx.x;
  if (i >= NSRC + NTGT) return;
  const float* base = (i < NSRC) ? (S + (size_t)i * DIM)
                                 : (T + (size_t)(i - NSRC) * DIM);
  const float4* p = (const float4*)base;
  float a = 0.f;
#pragma unroll
  for (int k = 0; k < DIM / 4; ++k) {
    float4 v = p[k];
    a += v.x * v.x + v.y * v.y + v.z * v.z + v.w * v.w;
  }
  if (i < NSRC) s2[i] = a;
  else          t2[i - NSRC] = a;
}

// ---------------------------------------------------------------------------
// kernel 2: per-call init. c[]=0 (fallback colsum accumulator), v=1.
// ---------------------------------------------------------------------------
__global__ __launch_bounds__(256) void init_k(float* __restrict__ c,
                                              float* __restrict__ v_out) {
  int i = blockIdx.x * 256 + threadIdx.x;
  if (i < NTGT) {
    c[i] = 0.f;
    v_out[i] = 1.f;
  }
}

// ---------------------------------------------------------------------------
// kernel 3: build K = exp(-cost/eps). bf16 K always; f32 K only for fallback.
// ---------------------------------------------------------------------------
#define BM 64
#define BN 128
__global__ __launch_bounds__(256) void kbuild_k(const float* __restrict__ S,
                                                const float* __restrict__ T,
                                                const float* __restrict__ s2,
                                                const float* __restrict__ t2,
                                                float* __restrict__ Kf,
                                                __hip_bfloat16* __restrict__ Kb) {
  __shared__ float sT[BM][68];
  __shared__ float tT[BN][68];
  const int bn = blockIdx.x * BN;
  const int bm = blockIdx.y * BM;
  const int tid = threadIdx.x;

  {
    const float4* sg = (const float4*)(S + (size_t)bm * DIM);
#pragma unroll
    for (int k = 0; k < 4; ++k) {
      int f = tid + 256 * k;
      int row = f >> 4, c4 = f & 15;
      *(float4*)&sT[row][c4 * 4] = sg[f];
    }
    const float4* tg = (const float4*)(T + (size_t)bn * DIM);
#pragma unroll
    for (int k = 0; k < 8; ++k) {
      int f = tid + 256 * k;
      int row = f >> 4, c4 = f & 15;
      *(float4*)&tT[row][c4 * 4] = tg[f];
    }
  }
  __syncthreads();

  const int tx = tid & 15;
  const int ty = tid >> 4;

  float acc[4][8];
#pragma unroll
  for (int a = 0; a < 4; ++a)
#pragma unroll
    for (int b = 0; b < 8; ++b) acc[a][b] = 0.f;

  for (int k = 0; k < DIM; k += 4) {
    float4 sr[4], tr[8];
#pragma unroll
    for (int a = 0; a < 4; ++a) sr[a] = *(float4*)&sT[ty + 16 * a][k];
#pragma unroll
    for (int b = 0; b < 8; ++b) tr[b] = *(float4*)&tT[tx + 16 * b][k];
#pragma unroll
    for (int a = 0; a < 4; ++a)
#pragma unroll
      for (int b = 0; b < 8; ++b) {
        acc[a][b] += sr[a].x * tr[b].x;
        acc[a][b] += sr[a].y * tr[b].y;
        acc[a][b] += sr[a].z * tr[b].z;
        acc[a][b] += sr[a].w * tr[b].w;
      }
  }

#pragma unroll
  for (int a = 0; a < 4; ++a) {
    int gi = bm + ty + 16 * a;
    float s2v = s2[gi];
#pragma unroll
    for (int b = 0; b < 8; ++b) {
      int gj = bn + tx + 16 * b;
      float sq = s2v + t2[gj] - 2.f * acc[a][b];
      float cost = sqrtf(fmaxf(sq, 0.f));
      float kv = __expf(-10.f * cost);  // 1/eps = 10
      size_t off = (size_t)gi * NTGT + gj;
      if (Kf) Kf[off] = kv;
      Kb[off] = __float2bfloat16(kv);
    }
  }
}

// ---------------------------------------------------------------------------
// kernel F3: fused iteration, wave-independent rows.
// Block = 256 thr, 16 rows; each WAVE owns 4 consecutive rows (no block sync
// in the row loop). Lane owns col-blocks 8*(lane+64s), s=0..15.
// Per row: dot(K_row, v) with v read from global (L2-resident, 32 KB),
// butterfly-reduce (all lanes get sum), u_i = sw/(sum+stab), accumulate
// K_row*u_i into block LDS accumulator cacc via ds_add (atomicAdd on LDS).
// cacc layout transposed: col j=8m+e lives at p = 1024*e + m -> each ds_add
// is lane-consecutive (conflict-free). Flush cacc -> c_part[block][8192].
// ---------------------------------------------------------------------------
#define F3_ROWS 16
#define F3_BLOCKS (NSRC / F3_ROWS)  // 512

__global__ __launch_bounds__(256, 2) void fused3_k(
    const unsigned short* __restrict__ Kb,
    const float* __restrict__ v,
    float* __restrict__ u_out,
    float* __restrict__ c_part) {
  __shared__ float cacc[8192];
  const int tid = threadIdx.x;
  const int w = tid >> 6, lane = tid & 63;

#pragma unroll
  for (int k = 0; k < 32; ++k) cacc[tid + 256 * k] = 0.f;
  __syncthreads();

  const int rbase = blockIdx.x * F3_ROWS + w * 4;
  uint4 qa[16], qb[16];
  {
    const uint4* rp = (const uint4*)(Kb + (size_t)rbase * NTGT);
#pragma unroll
    for (int s = 0; s < 16; ++s) qa[s] = rp[lane + 64 * s];
  }

#define F3_BODY(QC, QN, RR)                                                    \
  {                                                                            \
    const int row = rbase + (RR);                                              \
    if ((RR) < 3) {                                                            \
      const uint4* rp = (const uint4*)(Kb + (size_t)(row + 1) * NTGT);         \
      _Pragma("unroll")                                                        \
      for (int s = 0; s < 16; ++s) QN[s] = rp[lane + 64 * s];                  \
    }                                                                          \
    float d = 0.f;                                                             \
    _Pragma("unroll")                                                          \
    for (int s = 0; s < 16; ++s) {                                             \
      const float4* vp = (const float4*)(v + 8 * (lane + 64 * s));             \
      float4 va = vp[0], vb = vp[1];                                           \
      d += bflo(QC[s].x) * va.x + bfhi(QC[s].x) * va.y                         \
         + bflo(QC[s].y) * va.z + bfhi(QC[s].y) * va.w                         \
         + bflo(QC[s].z) * vb.x + bfhi(QC[s].z) * vb.y                         \
         + bflo(QC[s].w) * vb.z + bfhi(QC[s].w) * vb.w;                        \
    }                                                                          \
    _Pragma("unroll")                                                          \
    for (int off = 32; off > 0; off >>= 1) d += __shfl_xor(d, off, 64);        \
    float ui = (1.0f / NSRC) / (d + 1e-8f);                                    \
    if (lane == 0) u_out[row] = ui;                                            \
    _Pragma("unroll")                                                          \
    for (int s = 0; s < 16; ++s) {                                             \
      int m = lane + 64 * s;                                                   \
      atomicAdd(&cacc[0 * 1024 + m], bflo(QC[s].x) * ui);                      \
      atomicAdd(&cacc[1 * 1024 + m], bfhi(QC[s].x) * ui);                      \
      atomicAdd(&cacc[2 * 1024 + m], bflo(QC[s].y) * ui);                      \
      atomicAdd(&cacc[3 * 1024 + m], bfhi(QC[s].y) * ui);                      \
      atomicAdd(&cacc[4 * 1024 + m], bflo(QC[s].z) * ui);                      \
      atomicAdd(&cacc[5 * 1024 + m], bfhi(QC[s].z) * ui);                      \
      atomicAdd(&cacc[6 * 1024 + m], bflo(QC[s].w) * ui);                      \
      atomicAdd(&cacc[7 * 1024 + m], bfhi(QC[s].w) * ui);                      \
    }                                                                          \
  }

  F3_BODY(qa, qb, 0)
  F3_BODY(qb, qa, 1)
  F3_BODY(qa, qb, 2)
  F3_BODY(qb, qa, 3)
#undef F3_BODY

  __syncthreads();
  float* dst = c_part + (size_t)blockIdx.x * 8192;
#pragma unroll
  for (int k = 0; k < 32; ++k)
    dst[tid + 256 * k] = cacc[tid + 256 * k];
}

// ---------------------------------------------------------------------------
// kernel F2: stage-1 column reduce: c2[sl][p] = sum over 64 blocks of c_part.
// grid (32, 8); coalesced (fixed p across lanes).
// ---------------------------------------------------------------------------
__global__ __launch_bounds__(256) void csum1_k(const float* __restrict__ c_part,
                                               float* __restrict__ c2) {
  int p = blockIdx.x * 256 + threadIdx.x;
  const float* base = c_part + (size_t)(blockIdx.y * 64) * 8192 + p;
  float a = 0.f;
#pragma unroll 8
  for (int m = 0; m < 64; ++m) a += base[(size_t)m * 8192];
  c2[(size_t)blockIdx.y * 8192 + p] = a;
}

// ---------------------------------------------------------------------------
// kernel F3b: stage-2: v[j] = tw / (sum_sl c2[sl][p(j)] + stab).
// p(j) = (j>>3) + 1024*(j&7)  (matches cacc layout: col j=8m+e at 1024e+m)
// ---------------------------------------------------------------------------
__global__ __launch_bounds__(256) void csum2_k(const float* __restrict__ c2,
                                               float* __restrict__ v_out) {
  int j = blockIdx.x * 256 + threadIdx.x;
  int p = (j >> 3) + 1024 * (j & 7);
  float a = 0.f;
#pragma unroll
  for (int sl = 0; sl < 8; ++sl) a += c2[(size_t)sl * 8192 + p];
  v_out[j] = (1.0f / NTGT) / (a + 1e-8f);
}

// ---------------------------------------------------------------------------
// kernel C: coupling from bf16 K: C = u*Kb*v (f32 out), dist partials via
// cost = -0.1*ln(Kb). Guard ln against bf16 underflow (c is 0 there anyway).
// ---------------------------------------------------------------------------
__global__ __launch_bounds__(256) void coupling_bf16_k(
    const unsigned short* __restrict__ Kb,
    const float* __restrict__ u,
    const float* __restrict__ v,
    float* __restrict__ C,
    float* __restrict__ partials) {
  __shared__ float red[4];
  size_t g = (size_t)blockIdx.x * 256 + threadIdx.x;  // 32-elem chunk index
  size_t base = g * 32;
  int i = (int)(base >> 13);
  int j0 = (int)(base & 8191);
  float ui = u[i];
  const uint4* kp = (const uint4*)(Kb + base);
  const float4* vp = (const float4*)(v + j0);
  float part = 0.f;
#pragma unroll
  for (int s = 0; s < 4; ++s) {
    uint4 q = kp[s];
    float4 va = vp[2 * s], vb = vp[2 * s + 1];
    float k0 = bflo(q.x), k1 = bfhi(q.x), k2 = bflo(q.y), k3 = bfhi(q.y);
    float k4 = bflo(q.z), k5 = bfhi(q.z), k6 = bflo(q.w), k7 = bfhi(q.w);
    float c0 = ui * k0 * va.x, c1 = ui * k1 * va.y;
    float c2 = ui * k2 * va.z, c3 = ui * k3 * va.w;
    float c4 = ui * k4 * vb.x, c5 = ui * k5 * vb.y;
    float c6 = ui * k6 * vb.z, c7 = ui * k7 * vb.w;
    part += c0 * __logf(fmaxf(k0, 1e-37f)) + c1 * __logf(fmaxf(k1, 1e-37f)) +
            c2 * __logf(fmaxf(k2, 1e-37f)) + c3 * __logf(fmaxf(k3, 1e-37f)) +
            c4 * __logf(fmaxf(k4, 1e-37f)) + c5 * __logf(fmaxf(k5, 1e-37f)) +
            c6 * __logf(fmaxf(k6, 1e-37f)) + c7 * __logf(fmaxf(k7, 1e-37f));
    float* cw = C + base + 8 * s;
    *(float4*)cw       = make_float4(c0, c1, c2, c3);
    *(float4*)(cw + 4) = make_float4(c4, c5, c6, c7);
  }
  part = wave_reduce_sum(part);
  int wid = threadIdx.x >> 6, lane = threadIdx.x & 63;
  if (lane == 0) red[wid] = part;
  __syncthreads();
  if (threadIdx.x == 0)
    partials[blockIdx.x] = red[0] + red[1] + red[2] + red[3];
}

// ---------------------------------------------------------------------------
// fallback kernels (round-2 proven path; only used if ws too small)
// ---------------------------------------------------------------------------
__global__ __launch_bounds__(256) void rowsum_bf16_k(const unsigned short* __restrict__ Kb,
                                                     const float* __restrict__ v,
                                                     float* __restrict__ u_out) {
  int row = (blockIdx.x * 256 + threadIdx.x) >> 6;
  int lane = threadIdx.x & 63;
  const uint4* r4 = (const uint4*)(Kb + (size_t)row * NTGT);
  const float4* v4 = (const float4*)v;
  float a = 0.f;
#pragma unroll 4
  for (int it = lane; it < NTGT / 8; it += 64) {
    uint4 q = r4[it];
    float4 v0 = v4[it * 2];
    float4 v1 = v4[it * 2 + 1];
    a += bflo(q.x) * v0.x + bfhi(q.x) * v0.y;
    a += bflo(q.y) * v0.z + bfhi(q.y) * v0.w;
    a += bflo(q.z) * v1.x + bfhi(q.z) * v1.y;
    a += bflo(q.w) * v1.z + bfhi(q.w) * v1.w;
  }
  a = wave_reduce_sum(a);
  if (lane == 0) u_out[row] = (1.0f / NSRC) / (a + 1e-8f);
}

__global__ __launch_bounds__(256) void colsum_bf16_k(const unsigned short* __restrict__ Kb,
                                                     const float* __restrict__ u,
                                                     float* __restrict__ c) {
  int j = blockIdx.x * 2048 + threadIdx.x * 8;
  int i0 = blockIdx.y * 64;
  float a0 = 0.f, a1 = 0.f, a2 = 0.f, a3 = 0.f;
  float a4 = 0.f, a5 = 0.f, a6 = 0.f, a7 = 0.f;
#pragma unroll 8
  for (int i = i0; i < i0 + 64; ++i) {
    float ui = u[i];
    uint4 q = *(const uint4*)(Kb + (size_t)i * NTGT + j);
    a0 += bflo(q.x) * ui; a1 += bfhi(q.x) * ui;
    a2 += bflo(q.y) * ui; a3 += bfhi(q.y) * ui;
    a4 += bflo(q.z) * ui; a5 += bfhi(q.z) * ui;
    a6 += bflo(q.w) * ui; a7 += bfhi(q.w) * ui;
  }
  atomicAdd(&c[j + 0], a0); atomicAdd(&c[j + 1], a1);
  atomicAdd(&c[j + 2], a2); atomicAdd(&c[j + 3], a3);
  atomicAdd(&c[j + 4], a4); atomicAdd(&c[j + 5], a5);
  atomicAdd(&c[j + 6], a6); atomicAdd(&c[j + 7], a7);
}

__global__ __launch_bounds__(256) void finishv_k(float* __restrict__ c,
                                                 float* __restrict__ v_out) {
  int j = blockIdx.x * 256 + threadIdx.x;
  v_out[j] = (1.0f / NTGT) / (c[j] + 1e-8f);
  c[j] = 0.f;
}

__global__ __launch_bounds__(256) void rowsum_k(const float* __restrict__ K,
                                                const float* __restrict__ v,
                                                float* __restrict__ u_out) {
  int row = (blockIdx.x * 256 + threadIdx.x) >> 6;
  int lane = threadIdx.x & 63;
  const float4* r4 = (const float4*)(K + (size_t)row * NTGT);
  const float4* v4 = (const float4*)v;
  float a = 0.f;
#pragma unroll 4
  for (int j = lane; j < NTGT / 4; j += 64) {
    float4 k4 = r4[j];
    float4 vv = v4[j];
    a += k4.x * vv.x + k4.y * vv.y + k4.z * vv.z + k4.w * vv.w;
  }
  a = wave_reduce_sum(a);
  if (lane == 0) u_out[row] = (1.0f / NSRC) / (a + 1e-8f);
}

__global__ __launch_bounds__(256) void colsum_k(const float* __restrict__ K,
                                                const float* __restrict__ u,
                                                float* __restrict__ c) {
  int j = blockIdx.x * 1024 + threadIdx.x * 4;
  int i0 = blockIdx.y * 64;
  float a0 = 0.f, a1 = 0.f, a2 = 0.f, a3 = 0.f;
#pragma unroll 8
  for (int i = i0; i < i0 + 64; ++i) {
    float ui = u[i];
    float4 k4 = *(const float4*)(K + (size_t)i * NTGT + j);
    a0 += k4.x * ui; a1 += k4.y * ui; a2 += k4.z * ui; a3 += k4.w * ui;
  }
  atomicAdd(&c[j + 0], a0);
  atomicAdd(&c[j + 1], a1);
  atomicAdd(&c[j + 2], a2);
  atomicAdd(&c[j + 3], a3);
}

__global__ __launch_bounds__(256) void coupling_k(float* __restrict__ K,
                                                  const float* __restrict__ u,
                                                  const float* __restrict__ v,
                                                  float* __restrict__ partials) {
  __shared__ float red[4];
  size_t t0 = (size_t)blockIdx.x * 2048 + threadIdx.x;
  float part = 0.f;
#pragma unroll
  for (int s = 0; s < 8; ++s) {
    size_t f4 = t0 + (size_t)s * 256;
    size_t base = f4 * 4;
    int i = (int)(base >> 13);
    int j = (int)(base & 8191);
    float4 k4 = *(float4*)(K + base);
    float ui = u[i];
    float4 vv = *(const float4*)(v + j);
    float c0 = ui * k4.x * vv.x;
    float c1 = ui * k4.y * vv.y;
    float c2 = ui * k4.z * vv.z;
    float c3 = ui * k4.w * vv.w;
    part += c0 * __logf(k4.x) + c1 * __logf(k4.y) +
            c2 * __logf(k4.z) + c3 * __logf(k4.w);
    *(float4*)(K + base) = make_float4(c0, c1, c2, c3);
  }
  part = wave_reduce_sum(part);
  int wid = threadIdx.x >> 6, lane = threadIdx.x & 63;
  if (lane == 0) red[wid] = part;
  __syncthreads();
  if (threadIdx.x == 0)
    partials[blockIdx.x] = red[0] + red[1] + red[2] + red[3];
}

// ---------------------------------------------------------------------------
// kernel 8: dist = -eps * sum(partials) / (ns*nt)
// ---------------------------------------------------------------------------
__global__ __launch_bounds__(256) void finalize_k(const float* __restrict__ partials,
                                                  float* __restrict__ out) {
  __shared__ float red[4];
  float a = 0.f;
  for (int i = threadIdx.x; i < 8192; i += 256) a += partials[i];
  a = wave_reduce_sum(a);
  int wid = threadIdx.x >> 6, lane = threadIdx.x & 63;
  if (lane == 0) red[wid] = a;
  __syncthreads();
  if (threadIdx.x == 0)
    out[0] = (red[0] + red[1] + red[2] + red[3]) *
             (-0.1f / ((float)NSRC * (float)NTGT));
}

// ---------------------------------------------------------------------------
extern "C" void kernel_launch(void* const* d_in, const int* in_sizes, int n_in,
                              void* d_out, int out_size, void* d_ws, size_t ws_size,
                              hipStream_t stream) {
  const float* S = (const float*)d_in[0];
  const float* T = (const float*)d_in[1];
  float* out = (float*)d_out;

  // output layout: [dist(1)][coupling(64M)][u(8192)][v(8192)]
  float* C  = out + 1;
  float* u  = out + 1 + (size_t)NSRC * NTGT;
  float* vv = u + NSRC;

  // ws byte layout:
  //   s2       @ 0     (32 KB)
  //   t2       @ 32K   (32 KB)
  //   c2       @ 64K   (256 KB)
  //   partials @ 320K  (32 KB)
  //   c        @ 352K  (32 KB)  (fallback accumulator)
  //   Kb       @ 512K  (128 MB)
  //   c_part   @ 512K+128M (16 MB)   -- same footprint round 3 proved fits
  char* wsb = (char*)d_ws;
  float* s2       = (float*)(wsb);
  float* t2       = (float*)(wsb + (32 << 10));
  float* c2       = (float*)(wsb + (64 << 10));
  float* partials = (float*)(wsb + (320 << 10));
  float* c        = (float*)(wsb + (352 << 10));
  const size_t KB_OFF = 512 << 10;
  const size_t KB_BYTES = (size_t)NSRC * NTGT * 2;        // 128 MB
  const size_t CP_OFF = KB_OFF + KB_BYTES;
  const size_t CP_BYTES = (size_t)F3_BLOCKS * NTGT * 4;   // 16 MB
  __hip_bfloat16* Kb = (__hip_bfloat16*)(wsb + KB_OFF);
  float* c_part = (float*)(wsb + CP_OFF);

  bool full = ws_size >= CP_OFF + CP_BYTES;
  bool mid  = ws_size >= KB_OFF + KB_BYTES;

  norms_k<<<(NSRC + NTGT + 255) / 256, 256, 0, stream>>>(S, T, s2, t2);
  init_k<<<NTGT / 256, 256, 0, stream>>>(c, vv);

  if (full) {
    kbuild_k<<<dim3(NTGT / BN, NSRC / BM), 256, 0, stream>>>(S, T, s2, t2,
                                                             nullptr, Kb);
    for (int it = 0; it < 10; ++it) {
      fused3_k<<<F3_BLOCKS, 256, 0, stream>>>(
          (const unsigned short*)Kb, vv, u, c_part);
      csum1_k<<<dim3(32, 8), 256, 0, stream>>>(c_part, c2);
      csum2_k<<<32, 256, 0, stream>>>(c2, vv);
    }
    coupling_bf16_k<<<8192, 256, 0, stream>>>(
        (const unsigned short*)Kb, u, vv, C, partials);
  } else if (mid) {
    kbuild_k<<<dim3(NTGT / BN, NSRC / BM), 256, 0, stream>>>(S, T, s2, t2,
                                                             C, Kb);
    for (int it = 0; it < 10; ++it) {
      rowsum_bf16_k<<<NSRC * 64 / 256, 256, 0, stream>>>(
          (const unsigned short*)Kb, vv, u);
      colsum_bf16_k<<<dim3(4, 128), 256, 0, stream>>>(
          (const unsigned short*)Kb, u, c);
      finishv_k<<<NTGT / 256, 256, 0, stream>>>(c, vv);
    }
    coupling_k<<<8192, 256, 0, stream>>>(C, u, vv, partials);
  } else {
    kbuild_k<<<dim3(NTGT / BN, NSRC / BM), 256, 0, stream>>>(S, T, s2, t2,
                                                             C, Kb /*unused*/);
    for (int it = 0; it < 10; ++it) {
      rowsum_k<<<NSRC * 64 / 256, 256, 0, stream>>>(C, vv, u);
      colsum_k<<<dim3(8, 128), 256, 0, stream>>>(C, u, c);
      finishv_k<<<NTGT / 256, 256, 0, stream>>>(c, vv);
    }
    coupling_k<<<8192, 256, 0, stream>>>(C, u, vv, partials);
  }
  finalize_k<<<1, 256, 0, stream>>>(partials, out);
}

// Round 6
// 778.401 us; speedup vs baseline: 4.9666x; 4.9666x over previous
//
#include <hip/hip_runtime.h>
#include <hip/hip_bf16.h>
#include <math.h>

#define NSRC 8192
#define NTGT 8192
#define DIM 64

// ---------------------------------------------------------------------------
// helpers
// ---------------------------------------------------------------------------
__device__ __forceinline__ float wave_reduce_sum(float x) {
#pragma unroll
  for (int off = 32; off > 0; off >>= 1) x += __shfl_down(x, off, 64);
  return x;
}

__device__ __forceinline__ float bflo(unsigned int u) {  // low bf16 of a u32
  return __uint_as_float(u << 16);
}
__device__ __forceinline__ float bfhi(unsigned int u) {  // high bf16 of a u32
  return __uint_as_float(u & 0xFFFF0000u);
}

// ---------------------------------------------------------------------------
// kernel 1: squared norms of source rows and target rows
// ---------------------------------------------------------------------------
__global__ __launch_bounds__(256) void norms_k(const float* __restrict__ S,
                                               const float* __restrict__ T,
                                               float* __restrict__ s2,
                                               float* __restrict__ t2) {
  int i = blockIdx.x * 256 + threadIdx.x;
  if (i >= NSRC + NTGT) return;
  const float* base = (i < NSRC) ? (S + (size_t)i * DIM)
                                 : (T + (size_t)(i - NSRC) * DIM);
  const float4* p = (const float4*)base;
  float a = 0.f;
#pragma unroll
  for (int k = 0; k < DIM / 4; ++k) {
    float4 v = p[k];
    a += v.x * v.x + v.y * v.y + v.z * v.z + v.w * v.w;
  }
  if (i < NSRC) s2[i] = a;
  else          t2[i - NSRC] = a;
}

// ---------------------------------------------------------------------------
// kernel 2: per-call init. v=1; c=0 only needed by the f32 fallback path.
// ---------------------------------------------------------------------------
__global__ __launch_bounds__(256) void init_k(float* __restrict__ c,
                                              float* __restrict__ v_out) {
  int i = blockIdx.x * 256 + threadIdx.x;
  if (i < NTGT) {
    c[i] = 0.f;
    v_out[i] = 1.f;
  }
}

// ---------------------------------------------------------------------------
// kernel 3: build K = exp(-cost/eps).
//  - Kb  (bf16, row-major)            -> ws           [main path]
//  - KbT (bf16, transposed row-major) -> d_out C area [main path]
//  - Kf  (f32)                        -> only for the fallback path
// Transpose staging reuses the 52 KB smem region after the dot loop
// (tr[128][72] ushort = 18.4 KB; row stride 144 B keeps 16 B alignment for
// the b128 LDS reads; writes are ~4-way bank aliased = cheap).
// ---------------------------------------------------------------------------
#define BM 64
#define BN 128
__global__ __launch_bounds__(256) void kbuild_k(const float* __restrict__ S,
                                                const float* __restrict__ T,
                                                const float* __restrict__ s2,
                                                const float* __restrict__ t2,
                                                float* __restrict__ Kf,
                                                __hip_bfloat16* __restrict__ Kb,
                                                __hip_bfloat16* __restrict__ KbT) {
  __shared__ __align__(16) char smem[52224];
  float (*sT)[68] = (float (*)[68])smem;                       // 64 x 68 f32
  float (*tT)[68] = (float (*)[68])(smem + 17408);             // 128 x 68 f32
  unsigned short (*tr)[72] = (unsigned short (*)[72])smem;     // reuse: 128 x 72 bf16

  const int bn = blockIdx.x * BN;
  const int bm = blockIdx.y * BM;
  const int tid = threadIdx.x;

  {
    const float4* sg = (const float4*)(S + (size_t)bm * DIM);
#pragma unroll
    for (int k = 0; k < 4; ++k) {
      int f = tid + 256 * k;
      int row = f >> 4, c4 = f & 15;
      *(float4*)&sT[row][c4 * 4] = sg[f];
    }
    const float4* tg = (const float4*)(T + (size_t)bn * DIM);
#pragma unroll
    for (int k = 0; k < 8; ++k) {
      int f = tid + 256 * k;
      int row = f >> 4, c4 = f & 15;
      *(float4*)&tT[row][c4 * 4] = tg[f];
    }
  }
  __syncthreads();

  const int tx = tid & 15;   // col group: gj = bn + tx + 16b
  const int ty = tid >> 4;   // row group: gi = bm + ty + 16a

  float acc[4][8];
#pragma unroll
  for (int a = 0; a < 4; ++a)
#pragma unroll
    for (int b = 0; b < 8; ++b) acc[a][b] = 0.f;

  for (int k = 0; k < DIM; k += 4) {
    float4 sr[4], trg[8];
#pragma unroll
    for (int a = 0; a < 4; ++a) sr[a] = *(float4*)&sT[ty + 16 * a][k];
#pragma unroll
    for (int b = 0; b < 8; ++b) trg[b] = *(float4*)&tT[tx + 16 * b][k];
#pragma unroll
    for (int a = 0; a < 4; ++a)
#pragma unroll
      for (int b = 0; b < 8; ++b) {
        acc[a][b] += sr[a].x * trg[b].x;
        acc[a][b] += sr[a].y * trg[b].y;
        acc[a][b] += sr[a].z * trg[b].z;
        acc[a][b] += sr[a].w * trg[b].w;
      }
  }
  __syncthreads();  // all sT/tT reads done before smem reuse as tr

  float s2r[4];
#pragma unroll
  for (int a = 0; a < 4; ++a) s2r[a] = s2[bm + ty + 16 * a];

#pragma unroll
  for (int a = 0; a < 4; ++a) {
    int gi = bm + ty + 16 * a;
#pragma unroll
    for (int b = 0; b < 8; ++b) {
      int gj = bn + tx + 16 * b;
      float sq = s2r[a] + t2[gj] - 2.f * acc[a][b];
      float cost = sqrtf(fmaxf(sq, 0.f));
      float kv = __expf(-10.f * cost);  // 1/eps = 10
      size_t off = (size_t)gi * NTGT + gj;
      __hip_bfloat16 kb = __float2bfloat16(kv);
      if (Kf) Kf[off] = kv;
      if (Kb) Kb[off] = kb;
      if (KbT) tr[tx + 16 * b][ty + 16 * a] = __hip_bfloat16_raw(kb).x;
    }
  }

  if (KbT) {
    __syncthreads();
    // thread t: row r = t>>1 of the transposed tile, segment seg = t&1
    int r = tid >> 1, seg = tid & 1;
    const uint4* src = (const uint4*)&tr[r][seg * 32];  // 16B-aligned (144B rows)
    uint4 d0 = src[0], d1 = src[1], d2 = src[2], d3 = src[3];
    uint4* dst = (uint4*)(KbT + (size_t)(bn + r) * NSRC + bm + seg * 32);
    dst[0] = d0; dst[1] = d1; dst[2] = d2; dst[3] = d3;
  }
}

// ---------------------------------------------------------------------------
// kernel 4: generic scaled-reciprocal row-matvec over a bf16 matrix:
//   y[r] = (1/8192) / (sum_j P[r][j] * x[j] + 1e-8)
// One wave per row, 4 rows/block, 2048 blocks -> 32 waves/CU (max occupancy).
// Used for BOTH directions: P=Kb,x=v -> u   and   P=KbT,x=u -> v.
// ---------------------------------------------------------------------------
__global__ __launch_bounds__(256) void rowsum_k(const unsigned short* __restrict__ P,
                                                const float* __restrict__ x,
                                                float* __restrict__ y) {
  int row = blockIdx.x * 4 + (threadIdx.x >> 6);
  int lane = threadIdx.x & 63;
  const uint4* r4 = (const uint4*)(P + (size_t)row * NTGT);
  const float4* x4 = (const float4*)x;
  float a = 0.f;
#pragma unroll 4
  for (int s = lane; s < NTGT / 8; s += 64) {
    uint4 q = r4[s];
    float4 xa = x4[2 * s], xb = x4[2 * s + 1];
    a += bflo(q.x) * xa.x + bfhi(q.x) * xa.y
       + bflo(q.y) * xa.z + bfhi(q.y) * xa.w
       + bflo(q.z) * xb.x + bfhi(q.z) * xb.y
       + bflo(q.w) * xb.z + bfhi(q.w) * xb.w;
  }
  a = wave_reduce_sum(a);
  if (lane == 0) y[row] = (1.0f / 8192.0f) / (a + 1e-8f);
}

// ---------------------------------------------------------------------------
// kernel C: coupling from bf16 K: C = u*Kb*v (f32 out), dist partials via
// cost = -0.1*ln(Kb). Guard ln against bf16 underflow (c is 0 there anyway).
// Overwrites the C region (which held KbT) — KbT is dead by now; each C
// location is written exactly once and only Kb is read.
// ---------------------------------------------------------------------------
__global__ __launch_bounds__(256) void coupling_bf16_k(
    const unsigned short* __restrict__ Kb,
    const float* __restrict__ u,
    const float* __restrict__ v,
    float* __restrict__ C,
    float* __restrict__ partials) {
  __shared__ float red[4];
  size_t g = (size_t)blockIdx.x * 256 + threadIdx.x;  // 32-elem chunk index
  size_t base = g * 32;
  int i = (int)(base >> 13);
  int j0 = (int)(base & 8191);
  float ui = u[i];
  const uint4* kp = (const uint4*)(Kb + base);
  const float4* vp = (const float4*)(v + j0);
  float part = 0.f;
#pragma unroll
  for (int s = 0; s < 4; ++s) {
    uint4 q = kp[s];
    float4 va = vp[2 * s], vb = vp[2 * s + 1];
    float k0 = bflo(q.x), k1 = bfhi(q.x), k2 = bflo(q.y), k3 = bfhi(q.y);
    float k4 = bflo(q.z), k5 = bfhi(q.z), k6 = bflo(q.w), k7 = bfhi(q.w);
    float c0 = ui * k0 * va.x, c1 = ui * k1 * va.y;
    float c2 = ui * k2 * va.z, c3 = ui * k3 * va.w;
    float c4 = ui * k4 * vb.x, c5 = ui * k5 * vb.y;
    float c6 = ui * k6 * vb.z, c7 = ui * k7 * vb.w;
    part += c0 * __logf(fmaxf(k0, 1e-37f)) + c1 * __logf(fmaxf(k1, 1e-37f)) +
            c2 * __logf(fmaxf(k2, 1e-37f)) + c3 * __logf(fmaxf(k3, 1e-37f)) +
            c4 * __logf(fmaxf(k4, 1e-37f)) + c5 * __logf(fmaxf(k5, 1e-37f)) +
            c6 * __logf(fmaxf(k6, 1e-37f)) + c7 * __logf(fmaxf(k7, 1e-37f));
    float* cw = C + base + 8 * s;
    *(float4*)cw       = make_float4(c0, c1, c2, c3);
    *(float4*)(cw + 4) = make_float4(c4, c5, c6, c7);
  }
  part = wave_reduce_sum(part);
  int wid = threadIdx.x >> 6, lane = threadIdx.x & 63;
  if (lane == 0) red[wid] = part;
  __syncthreads();
  if (threadIdx.x == 0)
    partials[blockIdx.x] = red[0] + red[1] + red[2] + red[3];
}

// ---------------------------------------------------------------------------
// f32 fallback kernels (only if ws can't hold the 128 MB bf16 K — unproven
// branch kept for safety; main path needs only the round-3-proven footprint)
// ---------------------------------------------------------------------------
__global__ __launch_bounds__(256) void rowsum_f32_k(const float* __restrict__ K,
                                                    const float* __restrict__ v,
                                                    float* __restrict__ u_out) {
  int row = (blockIdx.x * 256 + threadIdx.x) >> 6;
  int lane = threadIdx.x & 63;
  const float4* r4 = (const float4*)(K + (size_t)row * NTGT);
  const float4* v4 = (const float4*)v;
  float a = 0.f;
#pragma unroll 4
  for (int j = lane; j < NTGT / 4; j += 64) {
    float4 k4 = r4[j];
    float4 vv = v4[j];
    a += k4.x * vv.x + k4.y * vv.y + k4.z * vv.z + k4.w * vv.w;
  }
  a = wave_reduce_sum(a);
  if (lane == 0) u_out[row] = (1.0f / NSRC) / (a + 1e-8f);
}

__global__ __launch_bounds__(256) void colsum_f32_k(const float* __restrict__ K,
                                                    const float* __restrict__ u,
                                                    float* __restrict__ c) {
  int j = blockIdx.x * 1024 + threadIdx.x * 4;
  int i0 = blockIdx.y * 64;
  float a0 = 0.f, a1 = 0.f, a2 = 0.f, a3 = 0.f;
#pragma unroll 8
  for (int i = i0; i < i0 + 64; ++i) {
    float ui = u[i];
    float4 k4 = *(const float4*)(K + (size_t)i * NTGT + j);
    a0 += k4.x * ui; a1 += k4.y * ui; a2 += k4.z * ui; a3 += k4.w * ui;
  }
  atomicAdd(&c[j + 0], a0);
  atomicAdd(&c[j + 1], a1);
  atomicAdd(&c[j + 2], a2);
  atomicAdd(&c[j + 3], a3);
}

__global__ __launch_bounds__(256) void finishv_k(float* __restrict__ c,
                                                 float* __restrict__ v_out) {
  int j = blockIdx.x * 256 + threadIdx.x;
  v_out[j] = (1.0f / NTGT) / (c[j] + 1e-8f);
  c[j] = 0.f;
}

__global__ __launch_bounds__(256) void coupling_f32_k(float* __restrict__ K,
                                                      const float* __restrict__ u,
                                                      const float* __restrict__ v,
                                                      float* __restrict__ partials) {
  __shared__ float red[4];
  size_t t0 = (size_t)blockIdx.x * 2048 + threadIdx.x;
  float part = 0.f;
#pragma unroll
  for (int s = 0; s < 8; ++s) {
    size_t f4 = t0 + (size_t)s * 256;
    size_t base = f4 * 4;
    int i = (int)(base >> 13);
    int j = (int)(base & 8191);
    float4 k4 = *(float4*)(K + base);
    float ui = u[i];
    float4 vv = *(const float4*)(v + j);
    float c0 = ui * k4.x * vv.x;
    float c1 = ui * k4.y * vv.y;
    float c2 = ui * k4.z * vv.z;
    float c3 = ui * k4.w * vv.w;
    part += c0 * __logf(k4.x) + c1 * __logf(k4.y) +
            c2 * __logf(k4.z) + c3 * __logf(k4.w);
    *(float4*)(K + base) = make_float4(c0, c1, c2, c3);
  }
  part = wave_reduce_sum(part);
  int wid = threadIdx.x >> 6, lane = threadIdx.x & 63;
  if (lane == 0) red[wid] = part;
  __syncthreads();
  if (threadIdx.x == 0)
    partials[blockIdx.x] = red[0] + red[1] + red[2] + red[3];
}

// ---------------------------------------------------------------------------
// kernel 8: dist = -eps * sum(partials) / (ns*nt)
// ---------------------------------------------------------------------------
__global__ __launch_bounds__(256) void finalize_k(const float* __restrict__ partials,
                                                  float* __restrict__ out) {
  __shared__ float red[4];
  float a = 0.f;
  for (int i = threadIdx.x; i < 8192; i += 256) a += partials[i];
  a = wave_reduce_sum(a);
  int wid = threadIdx.x >> 6, lane = threadIdx.x & 63;
  if (lane == 0) red[wid] = a;
  __syncthreads();
  if (threadIdx.x == 0)
    out[0] = (red[0] + red[1] + red[2] + red[3]) *
             (-0.1f / ((float)NSRC * (float)NTGT));
}

// ---------------------------------------------------------------------------
extern "C" void kernel_launch(void* const* d_in, const int* in_sizes, int n_in,
                              void* d_out, int out_size, void* d_ws, size_t ws_size,
                              hipStream_t stream) {
  const float* S = (const float*)d_in[0];
  const float* T = (const float*)d_in[1];
  float* out = (float*)d_out;

  // output layout: [dist(1)][coupling(64M)][u(8192)][v(8192)]
  float* C  = out + 1;
  float* u  = out + 1 + (size_t)NSRC * NTGT;
  float* vv = u + NSRC;

  // KbT lives in the C region during the iterations (dead until coupling).
  // Base is d_out+4 bytes: dword-aligned; dwordx4 at 4B alignment is
  // HW-supported (empirically proven by rounds 1-2 float4 ops at out+1).
  __hip_bfloat16* KbT = (__hip_bfloat16*)C;

  // ws byte layout:
  //   s2       @ 0     (32 KB)
  //   t2       @ 32K   (32 KB)
  //   partials @ 64K   (32 KB)
  //   c        @ 96K   (32 KB)   (fallback only)
  //   Kb       @ 512K  (128 MB)
  char* wsb = (char*)d_ws;
  float* s2       = (float*)(wsb);
  float* t2       = (float*)(wsb + (32 << 10));
  float* partials = (float*)(wsb + (64 << 10));
  float* c        = (float*)(wsb + (96 << 10));
  const size_t KB_OFF = 512 << 10;
  const size_t KB_BYTES = (size_t)NSRC * NTGT * 2;  // 128 MB
  __hip_bfloat16* Kb = (__hip_bfloat16*)(wsb + KB_OFF);

  bool full = ws_size >= KB_OFF + KB_BYTES;

  norms_k<<<(NSRC + NTGT + 255) / 256, 256, 0, stream>>>(S, T, s2, t2);
  init_k<<<NTGT / 256, 256, 0, stream>>>(c, vv);

  if (full) {
    kbuild_k<<<dim3(NTGT / BN, NSRC / BM), 256, 0, stream>>>(
        S, T, s2, t2, nullptr, Kb, KbT);
    for (int it = 0; it < 10; ++it) {
      rowsum_k<<<NSRC / 4, 256, 0, stream>>>((const unsigned short*)Kb, vv, u);
      rowsum_k<<<NTGT / 4, 256, 0, stream>>>((const unsigned short*)KbT, u, vv);
    }
    coupling_bf16_k<<<8192, 256, 0, stream>>>(
        (const unsigned short*)Kb, u, vv, C, partials);
  } else {
    kbuild_k<<<dim3(NTGT / BN, NSRC / BM), 256, 0, stream>>>(
        S, T, s2, t2, C, nullptr, nullptr);
    for (int it = 0; it < 10; ++it) {
      rowsum_f32_k<<<NSRC * 64 / 256, 256, 0, stream>>>(C, vv, u);
      colsum_f32_k<<<dim3(8, 128), 256, 0, stream>>>(C, u, c);
      finishv_k<<<NTGT / 256, 256, 0, stream>>>(c, vv);
    }
    coupling_f32_k<<<8192, 256, 0, stream>>>(C, u, vv, partials);
  }
  finalize_k<<<1, 256, 0, stream>>>(partials, out);
}

// Round 7
// 686.154 us; speedup vs baseline: 5.6343x; 1.1344x over previous
//
#include <hip/hip_runtime.h>
#include <hip/hip_bf16.h>
#include <math.h>

#define NSRC 8192
#define NTGT 8192
#define DIM 64

typedef short bf16x8 __attribute__((ext_vector_type(8)));
typedef float f32x16 __attribute__((ext_vector_type(16)));

// ---------------------------------------------------------------------------
// helpers
// ---------------------------------------------------------------------------
__device__ __forceinline__ float wave_reduce_sum(float x) {
#pragma unroll
  for (int off = 32; off > 0; off >>= 1) x += __shfl_down(x, off, 64);
  return x;
}

__device__ __forceinline__ float bflo(unsigned int u) {  // low bf16 of a u32
  return __uint_as_float(u << 16);
}
__device__ __forceinline__ float bfhi(unsigned int u) {  // high bf16 of a u32
  return __uint_as_float(u & 0xFFFF0000u);
}
__device__ __forceinline__ unsigned short f2bfr(float x) {
  __hip_bfloat16 b = __float2bfloat16(x);
  return __hip_bfloat16_raw(b).x;
}

// ---------------------------------------------------------------------------
// kernel 1: squared norms of source rows and target rows (f32 inputs)
// ---------------------------------------------------------------------------
__global__ __launch_bounds__(256) void norms_k(const float* __restrict__ S,
                                               const float* __restrict__ T,
                                               float* __restrict__ s2,
                                               float* __restrict__ t2) {
  int i = blockIdx.x * 256 + threadIdx.x;
  if (i >= NSRC + NTGT) return;
  const float* base = (i < NSRC) ? (S + (size_t)i * DIM)
                                 : (T + (size_t)(i - NSRC) * DIM);
  const float4* p = (const float4*)base;
  float a = 0.f;
#pragma unroll
  for (int k = 0; k < DIM / 4; ++k) {
    float4 v = p[k];
    a += v.x * v.x + v.y * v.y + v.z * v.z + v.w * v.w;
  }
  if (i < NSRC) s2[i] = a;
  else          t2[i - NSRC] = a;
}

// ---------------------------------------------------------------------------
// kernel 1b: split features into bf16 hi + bf16 lo (lo = x - float(hi)).
// 8 elems/thread; grid 512 covers S then T.
// ---------------------------------------------------------------------------
__global__ __launch_bounds__(256) void prep_k(const float* __restrict__ S,
                                              const float* __restrict__ T,
                                              unsigned short* __restrict__ Shi,
                                              unsigned short* __restrict__ Slo,
                                              unsigned short* __restrict__ Thi,
                                              unsigned short* __restrict__ Tlo) {
  int i = blockIdx.x * 256 + threadIdx.x;
  const float* src;
  unsigned short *dh, *dl;
  if (i < 65536) { src = S; dh = Shi; dl = Slo; }
  else { src = T; dh = Thi; dl = Tlo; i -= 65536; }
  const float4* p = (const float4*)(src + (size_t)i * 8);
  float4 x = p[0], y = p[1];
  float vals[8] = {x.x, x.y, x.z, x.w, y.x, y.y, y.z, y.w};
  unsigned int h[8], lo[8];
#pragma unroll
  for (int e = 0; e < 8; ++e) {
    unsigned short hr = f2bfr(vals[e]);
    h[e] = hr;
    lo[e] = f2bfr(vals[e] - bflo(hr));
  }
  uint4 hw = make_uint4(h[0] | (h[1] << 16), h[2] | (h[3] << 16),
                        h[4] | (h[5] << 16), h[6] | (h[7] << 16));
  uint4 lw = make_uint4(lo[0] | (lo[1] << 16), lo[2] | (lo[3] << 16),
                        lo[4] | (lo[5] << 16), lo[6] | (lo[7] << 16));
  *(uint4*)(dh + (size_t)i * 8) = hw;
  *(uint4*)(dl + (size_t)i * 8) = lw;
}

// ---------------------------------------------------------------------------
// kernel 2: per-call init. v=1, rowacc=0, c=0 (fallback).
// ---------------------------------------------------------------------------
__global__ __launch_bounds__(256) void init_k(float* __restrict__ c,
                                              float* __restrict__ v_out,
                                              float* __restrict__ rowacc) {
  int i = blockIdx.x * 256 + threadIdx.x;
  if (i < NTGT) {
    c[i] = 0.f;
    v_out[i] = 1.f;
    rowacc[i] = 0.f;
  }
}

// ---------------------------------------------------------------------------
// kernel 3 (main): MFMA K-build. 64x64 tile/block, 4 waves each 32x32.
// dot = S·T^T via 3 MFMAs per k-step (hi·hi + hi·lo + lo·hi, f32 accum).
// Epilogue: sq = s2+t2-2dot -> K = exp(-10*sqrt(max(sq,0))) -> bf16 staged in
// LDS with row-bit-swap swizzle PR(r) (kills the 8-apart-row bank collision
// in the transpose gather), then cooperative writes of Kb (row-major) and
// KbT (transposed), plus row-sum fold (v==1 first u-pass) into rowacc.
// ---------------------------------------------------------------------------
#define PR(r) ((((r) >> 3) + (((r)&7) << 3)))

__global__ __launch_bounds__(256) void kbuild_mfma_k(
    const unsigned short* __restrict__ Shi, const unsigned short* __restrict__ Slo,
    const unsigned short* __restrict__ Thi, const unsigned short* __restrict__ Tlo,
    const float* __restrict__ s2, const float* __restrict__ t2,
    __hip_bfloat16* __restrict__ Kb, __hip_bfloat16* __restrict__ KbT,
    float* __restrict__ rowacc) {
  __shared__ unsigned short sAh[64][72], sAl[64][72];
  __shared__ unsigned short sBh[64][72], sBl[64][72];
  __shared__ unsigned short stage[64][72];
  __shared__ float sS2[64], sT2[64];

  const int tid = threadIdx.x;
  const int bm = blockIdx.y * 64, bn = blockIdx.x * 64;

  // stage input tiles (each 64x64 bf16 contiguous = 512 uint4)
#pragma unroll
  for (int p = 0; p < 2; ++p) {
    int f = tid + 256 * p;
    int row = f >> 3, seg = (f & 7) * 8;
    *(uint4*)&sAh[row][seg] = ((const uint4*)(Shi + (size_t)bm * DIM))[f];
    *(uint4*)&sAl[row][seg] = ((const uint4*)(Slo + (size_t)bm * DIM))[f];
    *(uint4*)&sBh[row][seg] = ((const uint4*)(Thi + (size_t)bn * DIM))[f];
    *(uint4*)&sBl[row][seg] = ((const uint4*)(Tlo + (size_t)bn * DIM))[f];
  }
  if (tid < 64) sS2[tid] = s2[bm + tid];
  else if (tid < 128) sT2[tid - 64] = t2[bn + (tid - 64)];
  __syncthreads();

  const int w = tid >> 6, l = tid & 63;
  const int wr = w >> 1, wc = w & 1;
  const int arow = 32 * wr + (l & 31);
  const int brow = 32 * wc + (l & 31);
  const int kh = 8 * (l >> 5);

  f32x16 acc;
#pragma unroll
  for (int i = 0; i < 16; ++i) acc[i] = 0.f;

#pragma unroll
  for (int ks = 0; ks < 4; ++ks) {
    int ko = 16 * ks + kh;
    bf16x8 ah = *(const bf16x8*)&sAh[arow][ko];
    bf16x8 al = *(const bf16x8*)&sAl[arow][ko];
    bf16x8 bh = *(const bf16x8*)&sBh[brow][ko];
    bf16x8 bl = *(const bf16x8*)&sBl[brow][ko];
    acc = __builtin_amdgcn_mfma_f32_32x32x16_bf16(ah, bh, acc, 0, 0, 0);
    acc = __builtin_amdgcn_mfma_f32_32x32x16_bf16(ah, bl, acc, 0, 0, 0);
    acc = __builtin_amdgcn_mfma_f32_32x32x16_bf16(al, bh, acc, 0, 0, 0);
  }

  // epilogue -> swizzled LDS stage
#pragma unroll
  for (int j = 0; j < 16; ++j) {
    int rl = (j & 3) + 8 * (j >> 2) + 4 * (l >> 5);
    int row = 32 * wr + rl, col = 32 * wc + (l & 31);
    float sq = sS2[row] + sT2[col] - 2.f * acc[j];
    float kv = __expf(-10.f * sqrtf(fmaxf(sq, 0.f)));
    stage[PR(row)][col] = f2bfr(kv);
  }
  __syncthreads();

  // fold first u-pass: row sums (v==1) -> rowacc
  {
    int row = tid >> 2, q = tid & 3;
    float a = 0.f;
#pragma unroll
    for (int m = 0; m < 16; ++m)
      a += bflo((unsigned int)stage[PR(row)][16 * q + m]);
    a += __shfl_down(a, 1, 4);
    a += __shfl_down(a, 2, 4);
    if (q == 0) atomicAdd(&rowacc[bm + row], a);
  }

  // Kb write (row-major)
#pragma unroll
  for (int p = 0; p < 2; ++p) {
    int f = tid + 256 * p;
    int row = f >> 3, seg = (f & 7) * 8;
    *(uint4*)(Kb + (size_t)(bm + row) * NTGT + bn + seg) =
        *(const uint4*)&stage[PR(row)][seg];
  }
  // KbT write (transposed): thread owns (source col tcol, 8-row group gro)
#pragma unroll
  for (int p = 0; p < 2; ++p) {
    int f = tid + 256 * p;
    int tcol = f >> 3, gro = f & 7;
    unsigned int wds[4];
#pragma unroll
    for (int e = 0; e < 4; ++e) {
      // source rows r = 8*gro + 2e, 8*gro + 2e+1 ; PR(r) = gro + 8*(r&7)
      unsigned int a0 = stage[gro + 8 * (2 * e)][tcol];
      unsigned int a1 = stage[gro + 8 * (2 * e + 1)][tcol];
      wds[e] = a0 | (a1 << 16);
    }
    *(uint4*)(KbT + (size_t)(bn + tcol) * NSRC + bm + 8 * gro) =
        make_uint4(wds[0], wds[1], wds[2], wds[3]);
  }
}

// ---------------------------------------------------------------------------
// kernel 3b: u1 = sw / (rowacc + stab)
// ---------------------------------------------------------------------------
__global__ __launch_bounds__(256) void initu_k(const float* __restrict__ rowacc,
                                               float* __restrict__ u) {
  int i = blockIdx.x * 256 + threadIdx.x;
  u[i] = (1.0f / NSRC) / (rowacc[i] + 1e-8f);
}

// ---------------------------------------------------------------------------
// kernel 4: y[r] = (1/8192) / (sum_j P[r][j]*x[j] + 1e-8). One wave/row.
// ---------------------------------------------------------------------------
__global__ __launch_bounds__(256) void rowsum_k(const unsigned short* __restrict__ P,
                                                const float* __restrict__ x,
                                                float* __restrict__ y) {
  int row = blockIdx.x * 4 + (threadIdx.x >> 6);
  int lane = threadIdx.x & 63;
  const uint4* r4 = (const uint4*)(P + (size_t)row * NTGT);
  const float4* x4 = (const float4*)x;
  float a = 0.f;
#pragma unroll 4
  for (int s = lane; s < NTGT / 8; s += 64) {
    uint4 q = r4[s];
    float4 xa = x4[2 * s], xb = x4[2 * s + 1];
    a += bflo(q.x) * xa.x + bfhi(q.x) * xa.y
       + bflo(q.y) * xa.z + bfhi(q.y) * xa.w
       + bflo(q.z) * xb.x + bfhi(q.z) * xb.y
       + bflo(q.w) * xb.z + bfhi(q.w) * xb.w;
  }
  a = wave_reduce_sum(a);
  if (lane == 0) y[row] = (1.0f / 8192.0f) / (a + 1e-8f);
}

// ---------------------------------------------------------------------------
// kernel C: coupling C = u*Kb*v (f32), dist partials via cost = -0.1*ln(Kb).
// ---------------------------------------------------------------------------
__global__ __launch_bounds__(256) void coupling_bf16_k(
    const unsigned short* __restrict__ Kb,
    const float* __restrict__ u,
    const float* __restrict__ v,
    float* __restrict__ C,
    float* __restrict__ partials) {
  __shared__ float red[4];
  size_t g = (size_t)blockIdx.x * 256 + threadIdx.x;
  size_t base = g * 32;
  int i = (int)(base >> 13);
  int j0 = (int)(base & 8191);
  float ui = u[i];
  const uint4* kp = (const uint4*)(Kb + base);
  const float4* vp = (const float4*)(v + j0);
  float part = 0.f;
#pragma unroll
  for (int s = 0; s < 4; ++s) {
    uint4 q = kp[s];
    float4 va = vp[2 * s], vb = vp[2 * s + 1];
    float k0 = bflo(q.x), k1 = bfhi(q.x), k2 = bflo(q.y), k3 = bfhi(q.y);
    float k4 = bflo(q.z), k5 = bfhi(q.z), k6 = bflo(q.w), k7 = bfhi(q.w);
    float c0 = ui * k0 * va.x, c1 = ui * k1 * va.y;
    float c2 = ui * k2 * va.z, c3 = ui * k3 * va.w;
    float c4 = ui * k4 * vb.x, c5 = ui * k5 * vb.y;
    float c6 = ui * k6 * vb.z, c7 = ui * k7 * vb.w;
    part += c0 * __logf(fmaxf(k0, 1e-37f)) + c1 * __logf(fmaxf(k1, 1e-37f)) +
            c2 * __logf(fmaxf(k2, 1e-37f)) + c3 * __logf(fmaxf(k3, 1e-37f)) +
            c4 * __logf(fmaxf(k4, 1e-37f)) + c5 * __logf(fmaxf(k5, 1e-37f)) +
            c6 * __logf(fmaxf(k6, 1e-37f)) + c7 * __logf(fmaxf(k7, 1e-37f));
    float* cw = C + base + 8 * s;
    *(float4*)cw       = make_float4(c0, c1, c2, c3);
    *(float4*)(cw + 4) = make_float4(c4, c5, c6, c7);
  }
  part = wave_reduce_sum(part);
  int wid = threadIdx.x >> 6, lane = threadIdx.x & 63;
  if (lane == 0) red[wid] = part;
  __syncthreads();
  if (threadIdx.x == 0)
    partials[blockIdx.x] = red[0] + red[1] + red[2] + red[3];
}

// ---------------------------------------------------------------------------
// fallback kernels (f32 path; only if ws too small for main path)
// ---------------------------------------------------------------------------
#define BM 64
#define BN 128
__global__ __launch_bounds__(256) void kbuild_k(const float* __restrict__ S,
                                                const float* __restrict__ T,
                                                const float* __restrict__ s2,
                                                const float* __restrict__ t2,
                                                float* __restrict__ Kf) {
  __shared__ float sT[BM][68];
  __shared__ float tT[BN][68];
  const int bn = blockIdx.x * BN;
  const int bm = blockIdx.y * BM;
  const int tid = threadIdx.x;
  {
    const float4* sg = (const float4*)(S + (size_t)bm * DIM);
#pragma unroll
    for (int k = 0; k < 4; ++k) {
      int f = tid + 256 * k;
      int row = f >> 4, c4 = f & 15;
      *(float4*)&sT[row][c4 * 4] = sg[f];
    }
    const float4* tg = (const float4*)(T + (size_t)bn * DIM);
#pragma unroll
    for (int k = 0; k < 8; ++k) {
      int f = tid + 256 * k;
      int row = f >> 4, c4 = f & 15;
      *(float4*)&tT[row][c4 * 4] = tg[f];
    }
  }
  __syncthreads();
  const int tx = tid & 15;
  const int ty = tid >> 4;
  float acc[4][8];
#pragma unroll
  for (int a = 0; a < 4; ++a)
#pragma unroll
    for (int b = 0; b < 8; ++b) acc[a][b] = 0.f;
  for (int k = 0; k < DIM; k += 4) {
    float4 sr[4], trg[8];
#pragma unroll
    for (int a = 0; a < 4; ++a) sr[a] = *(float4*)&sT[ty + 16 * a][k];
#pragma unroll
    for (int b = 0; b < 8; ++b) trg[b] = *(float4*)&tT[tx + 16 * b][k];
#pragma unroll
    for (int a = 0; a < 4; ++a)
#pragma unroll
      for (int b = 0; b < 8; ++b) {
        acc[a][b] += sr[a].x * trg[b].x;
        acc[a][b] += sr[a].y * trg[b].y;
        acc[a][b] += sr[a].z * trg[b].z;
        acc[a][b] += sr[a].w * trg[b].w;
      }
  }
#pragma unroll
  for (int a = 0; a < 4; ++a) {
    int gi = bm + ty + 16 * a;
    float s2v = s2[gi];
#pragma unroll
    for (int b = 0; b < 8; ++b) {
      int gj = bn + tx + 16 * b;
      float sq = s2v + t2[gj] - 2.f * acc[a][b];
      float cost = sqrtf(fmaxf(sq, 0.f));
      Kf[(size_t)gi * NTGT + gj] = __expf(-10.f * cost);
    }
  }
}

__global__ __launch_bounds__(256) void rowsum_f32_k(const float* __restrict__ K,
                                                    const float* __restrict__ v,
                                                    float* __restrict__ u_out) {
  int row = (blockIdx.x * 256 + threadIdx.x) >> 6;
  int lane = threadIdx.x & 63;
  const float4* r4 = (const float4*)(K + (size_t)row * NTGT);
  const float4* v4 = (const float4*)v;
  float a = 0.f;
#pragma unroll 4
  for (int j = lane; j < NTGT / 4; j += 64) {
    float4 k4 = r4[j];
    float4 vv = v4[j];
    a += k4.x * vv.x + k4.y * vv.y + k4.z * vv.z + k4.w * vv.w;
  }
  a = wave_reduce_sum(a);
  if (lane == 0) u_out[row] = (1.0f / NSRC) / (a + 1e-8f);
}

__global__ __launch_bounds__(256) void colsum_f32_k(const float* __restrict__ K,
                                                    const float* __restrict__ u,
                                                    float* __restrict__ c) {
  int j = blockIdx.x * 1024 + threadIdx.x * 4;
  int i0 = blockIdx.y * 64;
  float a0 = 0.f, a1 = 0.f, a2 = 0.f, a3 = 0.f;
#pragma unroll 8
  for (int i = i0; i < i0 + 64; ++i) {
    float ui = u[i];
    float4 k4 = *(const float4*)(K + (size_t)i * NTGT + j);
    a0 += k4.x * ui; a1 += k4.y * ui; a2 += k4.z * ui; a3 += k4.w * ui;
  }
  atomicAdd(&c[j + 0], a0);
  atomicAdd(&c[j + 1], a1);
  atomicAdd(&c[j + 2], a2);
  atomicAdd(&c[j + 3], a3);
}

__global__ __launch_bounds__(256) void finishv_k(float* __restrict__ c,
                                                 float* __restrict__ v_out) {
  int j = blockIdx.x * 256 + threadIdx.x;
  v_out[j] = (1.0f / NTGT) / (c[j] + 1e-8f);
  c[j] = 0.f;
}

__global__ __launch_bounds__(256) void coupling_f32_k(float* __restrict__ K,
                                                      const float* __restrict__ u,
                                                      const float* __restrict__ v,
                                                      float* __restrict__ partials) {
  __shared__ float red[4];
  size_t t0 = (size_t)blockIdx.x * 2048 + threadIdx.x;
  float part = 0.f;
#pragma unroll
  for (int s = 0; s < 8; ++s) {
    size_t f4 = t0 + (size_t)s * 256;
    size_t base = f4 * 4;
    int i = (int)(base >> 13);
    int j = (int)(base & 8191);
    float4 k4 = *(float4*)(K + base);
    float ui = u[i];
    float4 vv = *(const float4*)(v + j);
    float c0 = ui * k4.x * vv.x;
    float c1 = ui * k4.y * vv.y;
    float c2 = ui * k4.z * vv.z;
    float c3 = ui * k4.w * vv.w;
    part += c0 * __logf(k4.x) + c1 * __logf(k4.y) +
            c2 * __logf(k4.z) + c3 * __logf(k4.w);
    *(float4*)(K + base) = make_float4(c0, c1, c2, c3);
  }
  part = wave_reduce_sum(part);
  int wid = threadIdx.x >> 6, lane = threadIdx.x & 63;
  if (lane == 0) red[wid] = part;
  __syncthreads();
  if (threadIdx.x == 0)
    partials[blockIdx.x] = red[0] + red[1] + red[2] + red[3];
}

// ---------------------------------------------------------------------------
// kernel 8: dist = -eps * sum(partials) / (ns*nt)
// ---------------------------------------------------------------------------
__global__ __launch_bounds__(256) void finalize_k(const float* __restrict__ partials,
                                                  float* __restrict__ out) {
  __shared__ float red[4];
  float a = 0.f;
  for (int i = threadIdx.x; i < 8192; i += 256) a += partials[i];
  a = wave_reduce_sum(a);
  int wid = threadIdx.x >> 6, lane = threadIdx.x & 63;
  if (lane == 0) red[wid] = a;
  __syncthreads();
  if (threadIdx.x == 0)
    out[0] = (red[0] + red[1] + red[2] + red[3]) *
             (-0.1f / ((float)NSRC * (float)NTGT));
}

// ---------------------------------------------------------------------------
extern "C" void kernel_launch(void* const* d_in, const int* in_sizes, int n_in,
                              void* d_out, int out_size, void* d_ws, size_t ws_size,
                              hipStream_t stream) {
  const float* S = (const float*)d_in[0];
  const float* T = (const float*)d_in[1];
  float* out = (float*)d_out;

  // output layout: [dist(1)][coupling(64M)][u(8192)][v(8192)]
  float* C  = out + 1;
  float* u  = out + 1 + (size_t)NSRC * NTGT;
  float* vv = u + NSRC;

  // KbT lives in the C region during the iterations (dead until coupling;
  // coupling overwrites every element). +4B base => dword-aligned, HW ok.
  __hip_bfloat16* KbT = (__hip_bfloat16*)C;

  // ws byte layout:
  //   s2 @0(32K) t2 @32K partials @64K c @96K rowacc @128K
  //   Shi @1M  Slo @2M  Thi @3M  Tlo @4M  (1 MB each)
  //   Kb  @8M  (128 MB)
  char* wsb = (char*)d_ws;
  float* s2       = (float*)(wsb);
  float* t2       = (float*)(wsb + (32 << 10));
  float* partials = (float*)(wsb + (64 << 10));
  float* c        = (float*)(wsb + (96 << 10));
  float* rowacc   = (float*)(wsb + (128 << 10));
  unsigned short* Shi = (unsigned short*)(wsb + (1 << 20));
  unsigned short* Slo = (unsigned short*)(wsb + (2 << 20));
  unsigned short* Thi = (unsigned short*)(wsb + (3 << 20));
  unsigned short* Tlo = (unsigned short*)(wsb + (4 << 20));
  const size_t KB_OFF = (size_t)8 << 20;
  const size_t KB_BYTES = (size_t)NSRC * NTGT * 2;  // 128 MB
  __hip_bfloat16* Kb = (__hip_bfloat16*)(wsb + KB_OFF);

  bool full = ws_size >= KB_OFF + KB_BYTES;  // 136 MB (proven available r3)

  norms_k<<<(NSRC + NTGT + 255) / 256, 256, 0, stream>>>(S, T, s2, t2);

  if (full) {
    prep_k<<<512, 256, 0, stream>>>(S, T, Shi, Slo, Thi, Tlo);
    init_k<<<NTGT / 256, 256, 0, stream>>>(c, vv, rowacc);
    kbuild_mfma_k<<<dim3(128, 128), 256, 0, stream>>>(
        Shi, Slo, Thi, Tlo, s2, t2, Kb, KbT, rowacc);
    initu_k<<<NSRC / 256, 256, 0, stream>>>(rowacc, u);
    for (int it = 0; it < 10; ++it) {
      if (it > 0)
        rowsum_k<<<NSRC / 4, 256, 0, stream>>>((const unsigned short*)Kb, vv, u);
      rowsum_k<<<NTGT / 4, 256, 0, stream>>>((const unsigned short*)KbT, u, vv);
    }
    coupling_bf16_k<<<8192, 256, 0, stream>>>(
        (const unsigned short*)Kb, u, vv, C, partials);
  } else {
    init_k<<<NTGT / 256, 256, 0, stream>>>(c, vv, partials /*dummy*/);
    kbuild_k<<<dim3(NTGT / BN, NSRC / BM), 256, 0, stream>>>(S, T, s2, t2, C);
    for (int it = 0; it < 10; ++it) {
      rowsum_f32_k<<<NSRC * 64 / 256, 256, 0, stream>>>(C, vv, u);
      colsum_f32_k<<<dim3(8, 128), 256, 0, stream>>>(C, u, c);
      finishv_k<<<NTGT / 256, 256, 0, stream>>>(c, vv);
    }
    coupling_f32_k<<<8192, 256, 0, stream>>>(C, u, vv, partials);
  }
  finalize_k<<<1, 256, 0, stream>>>(partials, out);
}